// Round 6
// baseline (206.122 us; speedup 1.0000x reference)
//
#include <hip/hip_runtime.h>
#include <hip/hip_bf16.h>

// Problem constants
#define B_    256
#define CIN   64
#define COUT  64
#define H_    1855
#define K_    6
#define KDIM  448          // (1 center + 6 neighbors) * 64 channels
#define NSTEP 14           // 448 / 32 (K per MFMA)
#define HT    64           // h-tile for transpose kernel
#define NHT   29           // ceil(1855/64)

// conv_main tiling
#define HT2   32           // h rows per conv tile
#define TPB   58           // tiles per b = ceil(1855/32)
#define NTILE (TPB * B_)   // 14848
#define TPBLK 8            // tiles per block
#define NBLK  (NTILE / TPBLK)   // 1856, % 8 == 0
#define CPX2  (NBLK / 8)        // 232

typedef __bf16 bf16x8 __attribute__((ext_vector_type(8)));
typedef float  f32x4  __attribute__((ext_vector_type(4)));

static __device__ inline unsigned short f2bf(float f) {
    __hip_bfloat16 h = __float2bfloat16(f);
    return *reinterpret_cast<unsigned short*>(&h);
}

// ---------------------------------------------------------------------------
// Kernel 1: pack weights into MFMA A-fragment order (bf16) + 1/total_valid
// Also zeroes the 128-B zbuf (branch-free source for invalid neighbors).
// ---------------------------------------------------------------------------
__global__ void prep_weights(const float* __restrict__ wc,
                             const float* __restrict__ wn,
                             const int*   __restrict__ nb,
                             unsigned short* __restrict__ W2,
                             float* __restrict__ inv_tv,
                             unsigned short* __restrict__ zbuf) {
    int e = blockIdx.x * 256 + threadIdx.x;     // 0 .. 28671
    int j = e & 7;
    int l = (e >> 3) & 63;
    int t = (e >> 9) & 3;
    int s = e >> 11;
    int o = t * 16 + (l & 15);
    int k = s * 32 + (l >> 4) * 8 + j;
    int slot = k >> 6;
    int c = k & 63;
    float v = (slot == 0) ? wc[o * 64 + c]
                          : wn[(o * 64 + c) * 6 + (slot - 1)];
    W2[e] = f2bf(v);
    if (blockIdx.x == 0 && threadIdx.x < 64) zbuf[threadIdx.x] = 0;
    if (e == 0) {
        int cnt = 1;
        #pragma unroll
        for (int q = 0; q < 6; ++q) cnt += (nb[q] >= 0) ? 1 : 0;
        *inv_tv = 1.0f / (float)cnt;
    }
}

// ---------------------------------------------------------------------------
// Kernel 2: transpose + convert  x (B, C, H) fp32  ->  xT (B, H, C) bf16
// ---------------------------------------------------------------------------
__global__ void transpose_bf16(const float* __restrict__ x,
                               unsigned short* __restrict__ xT) {
    __shared__ __align__(16) unsigned short tile[64][72];  // +8 pad
    int b  = blockIdx.y;
    int h0 = blockIdx.x * HT;
    int t  = threadIdx.x;
    int ho = t & 63;
    int cq = t >> 6;                       // 0..3
    const float* xb = x + (size_t)b * CIN * H_;
    int h = h0 + ho;
    #pragma unroll
    for (int i = 0; i < 16; ++i) {
        int c = i * 4 + cq;
        float v = (h < H_) ? xb[(size_t)c * H_ + h] : 0.f;
        tile[ho][c] = f2bf(v);
    }
    __syncthreads();
    #pragma unroll
    for (int rep = 0; rep < 2; ++rep) {
        int task = rep * 256 + t;          // 0..511  = 64 rows * 8 chunks
        int hh = task >> 3;
        int j  = task & 7;
        int hw = h0 + hh;
        if (hw < H_) {
            *reinterpret_cast<uint4*>(&xT[((size_t)b * H_ + hw) * 64 + j * 8]) =
                *reinterpret_cast<const uint4*>(&tile[hh][j * 8]);
        }
    }
}

// ---------------------------------------------------------------------------
// Kernel 3: direct-gather MFMA — NO LDS, NO barriers, NO staging.
// xT is L2/L3-resident (FETCH 38MB << 60.8MB); each lane loads its MFMA
// B-fragments (16B units) straight from global. 4 lanes/row at consecutive
// 16-B units merge into 64-B requests. W fragments VGPR-resident. nb indices
// prefetched one tile ahead. Waves run barrier-free; TLP hides L2 latency.
// 256 thr = 4 waves = 2 o-pairs x 2 h-subtiles; each wave: 14 loads ->
// 28 MFMA per tile.
// ---------------------------------------------------------------------------
__global__ __launch_bounds__(256, 3) void conv_main(
        const unsigned short* __restrict__ xT,
        const unsigned short* __restrict__ W2,
        const int*   __restrict__ nb,
        const float* __restrict__ bias,
        const float* __restrict__ inv_tv,
        const unsigned short* __restrict__ zbuf,
        float* __restrict__ out) {
    int bid = blockIdx.x;
    int swz   = (bid & 7) * CPX2 + (bid >> 3);   // bijective XCD swizzle
    int gbase = swz * TPBLK;

    int t = threadIdx.x;
    int w = t >> 6;          // wave 0..3
    int l = t & 63;

    int ogp = w & 1, hh = w >> 1;
    int lr = l & 15, lg = l >> 4;
    int hrow = hh * 16 + lr;            // 0..31

    // W fragments in VGPRs (validated layout)
    const bf16x8* __restrict__ Wf = reinterpret_cast<const bf16x8*>(W2);
    bf16x8 wr[NSTEP][2];
    #pragma unroll
    for (int s = 0; s < NSTEP; ++s)
        #pragma unroll
        for (int u = 0; u < 2; ++u)
            wr[s][u] = Wf[(s * 4 + ogp * 2 + u) * 64 + l];
    float inv = *inv_tv;
    float bv0[4], bv1[4];
    #pragma unroll
    for (int r = 0; r < 4; ++r) {
        bv0[r] = bias[ogp * 32 + lg * 4 + r];
        bv1[r] = bias[ogp * 32 + 16 + lg * 4 + r];
    }

    // prologue: neighbor indices for this lane's row of tile 0
    int nbv[6];
    {
        int g = gbase;
        int b0 = g / TPB;
        int h  = (g - b0 * TPB) * HT2 + hrow;
        #pragma unroll
        for (int q = 0; q < 6; ++q)
            nbv[q] = (h < H_) ? nb[h * 6 + q] : -1;
    }

    #pragma unroll 2
    for (int i = 0; i < TPBLK; ++i) {
        int g    = gbase + i;
        int curb = g / TPB;
        int h0   = (g - curb * TPB) * HT2;
        int h    = h0 + hrow;
        int hc   = (h < H_) ? h : (H_ - 1);   // clamp (results discarded)
        const unsigned short* xb = xT + (size_t)curb * H_ * 64;

        // capture this tile's neighbor rows, then prefetch next tile's
        int cn[6];
        #pragma unroll
        for (int q = 0; q < 6; ++q) cn[q] = nbv[q];
        if (i < TPBLK - 1) {
            int g1 = g + 1;
            int b1 = g1 / TPB;
            int hn = (g1 - b1 * TPB) * HT2 + hrow;
            #pragma unroll
            for (int q = 0; q < 6; ++q)
                nbv[q] = (hn < H_) ? nb[hn * 6 + q] : -1;
        }

        f32x4 acc0 = (f32x4){0.f, 0.f, 0.f, 0.f};
        f32x4 acc1 = (f32x4){0.f, 0.f, 0.f, 0.f};

        // center (k 0..63): per-lane coalesced-ish row reads
        {
            const bf16x8* crow = reinterpret_cast<const bf16x8*>(
                    xb + (size_t)hc * 64);
            bf16x8 f0 = crow[lg];
            bf16x8 f1 = crow[4 + lg];
            acc0 = __builtin_amdgcn_mfma_f32_16x16x32_bf16(wr[0][0], f0, acc0, 0, 0, 0);
            acc1 = __builtin_amdgcn_mfma_f32_16x16x32_bf16(wr[0][1], f0, acc1, 0, 0, 0);
            acc0 = __builtin_amdgcn_mfma_f32_16x16x32_bf16(wr[1][0], f1, acc0, 0, 0, 0);
            acc1 = __builtin_amdgcn_mfma_f32_16x16x32_bf16(wr[1][1], f1, acc1, 0, 0, 0);
        }

        // 6 neighbors (k 64..447): per-lane gathered row reads
        #pragma unroll
        for (int q = 0; q < 6; ++q) {
            int n = cn[q];
            const bf16x8* r = (n >= 0)
                ? reinterpret_cast<const bf16x8*>(xb + (size_t)n * 64)
                : reinterpret_cast<const bf16x8*>(zbuf);
            bf16x8 fa = r[lg];
            bf16x8 fb = r[4 + lg];
            int s = 2 + 2 * q;
            acc0 = __builtin_amdgcn_mfma_f32_16x16x32_bf16(wr[s][0],     fa, acc0, 0, 0, 0);
            acc1 = __builtin_amdgcn_mfma_f32_16x16x32_bf16(wr[s][1],     fa, acc1, 0, 0, 0);
            acc0 = __builtin_amdgcn_mfma_f32_16x16x32_bf16(wr[s + 1][0], fb, acc0, 0, 0, 0);
            acc1 = __builtin_amdgcn_mfma_f32_16x16x32_bf16(wr[s + 1][1], fb, acc1, 0, 0, 0);
        }

        // epilogue: 8 dword stores (64-B h-contiguous per 16-lane group)
        if (h < H_) {
            float* ob = out + (size_t)curb * COUT * H_ + h;
            #pragma unroll
            for (int r = 0; r < 4; ++r) {
                ob[(size_t)(ogp * 32 + lg * 4 + r) * H_]      = acc0[r] * inv + bv0[r];
                ob[(size_t)(ogp * 32 + 16 + lg * 4 + r) * H_] = acc1[r] * inv + bv1[r];
            }
        }
    }
}

// ---------------------------------------------------------------------------
extern "C" void kernel_launch(void* const* d_in, const int* in_sizes, int n_in,
                              void* d_out, int out_size, void* d_ws, size_t ws_size,
                              hipStream_t stream) {
    const float* x    = (const float*)d_in[0];
    const int*   nb   = (const int*)  d_in[1];
    const float* wc   = (const float*)d_in[2];
    const float* wn   = (const float*)d_in[3];
    const float* bias = (const float*)d_in[4];
    float* out = (float*)d_out;

    char* ws = (char*)d_ws;
    unsigned short* W2     = (unsigned short*)ws;            // 57,344 B
    float*          inv_tv = (float*)(ws + 57344);           // 4 B
    unsigned short* zbuf   = (unsigned short*)(ws + 57472);  // 128 B zero
    unsigned short* xT     = (unsigned short*)(ws + 57600);  // 60,784,640 B

    prep_weights<<<112, 256, 0, stream>>>(wc, wn, nb, W2, inv_tv, zbuf);

    dim3 tgrid(NHT, B_);
    transpose_bf16<<<tgrid, 256, 0, stream>>>(x, xT);
    conv_main<<<NBLK, 256, 0, stream>>>(xT, W2, nb, bias, inv_tv, zbuf, out);
}

// Round 7
// 129.652 us; speedup vs baseline: 1.5898x; 1.5898x over previous
//
#include <hip/hip_runtime.h>
#include <hip/hip_bf16.h>

// Problem constants
#define B_    256
#define CIN   64
#define COUT  64
#define H_    1855
#define K_    6
#define NSTEP 14           // 448 / 32 (K per MFMA)
#define HT    64           // h-tile for transpose kernel
#define NHT   29           // ceil(1855/64)

// conv_main tiling
#define HT2   32           // h rows per conv tile
#define TPB   58           // tiles per b = ceil(1855/32)
#define NTILE (TPB * B_)   // 14848
#define TPBLK 8            // tiles per block
#define NBLK  (NTILE / TPBLK)   // 1856, % 8 == 0
#define CPX2  (NBLK / 8)        // 232

typedef __bf16 bf16x8 __attribute__((ext_vector_type(8)));
typedef float  f32x4  __attribute__((ext_vector_type(4)));

typedef __attribute__((address_space(3))) unsigned int       lds_u32;
typedef const __attribute__((address_space(1))) unsigned int glb_u32;

static __device__ inline unsigned short f2bf(float f) {
    __hip_bfloat16 h = __float2bfloat16(f);
    return *reinterpret_cast<unsigned short*>(&h);
}

// ---------------------------------------------------------------------------
// Kernel 1: pack weights into MFMA A-fragment order (bf16) + 1/total_valid.
// Also zeroes the 128-B zbuf (branch-free source for invalid neighbors).
// ---------------------------------------------------------------------------
__global__ void prep_weights(const float* __restrict__ wc,
                             const float* __restrict__ wn,
                             const int*   __restrict__ nb,
                             unsigned short* __restrict__ W2,
                             float* __restrict__ inv_tv,
                             unsigned short* __restrict__ zbuf) {
    int e = blockIdx.x * 256 + threadIdx.x;     // 0 .. 28671
    int j = e & 7;
    int l = (e >> 3) & 63;
    int t = (e >> 9) & 3;
    int s = e >> 11;
    int o = t * 16 + (l & 15);
    int k = s * 32 + (l >> 4) * 8 + j;
    int slot = k >> 6;
    int c = k & 63;
    float v = (slot == 0) ? wc[o * 64 + c]
                          : wn[(o * 64 + c) * 6 + (slot - 1)];
    W2[e] = f2bf(v);
    if (blockIdx.x == 0 && threadIdx.x < 64) zbuf[threadIdx.x] = 0;
    if (e == 0) {
        int cnt = 1;
        #pragma unroll
        for (int q = 0; q < 6; ++q) cnt += (nb[q] >= 0) ? 1 : 0;
        *inv_tv = 1.0f / (float)cnt;
    }
}

// ---------------------------------------------------------------------------
// Kernel 2: transpose + convert  x (B, C, H) fp32  ->  xT (B, H, C) bf16
// ---------------------------------------------------------------------------
__global__ void transpose_bf16(const float* __restrict__ x,
                               unsigned short* __restrict__ xT) {
    __shared__ __align__(16) unsigned short tile[64][72];  // +8 pad
    int b  = blockIdx.y;
    int h0 = blockIdx.x * HT;
    int t  = threadIdx.x;
    int ho = t & 63;
    int cq = t >> 6;                       // 0..3
    const float* xb = x + (size_t)b * CIN * H_;
    int h = h0 + ho;
    #pragma unroll
    for (int i = 0; i < 16; ++i) {
        int c = i * 4 + cq;
        float v = (h < H_) ? xb[(size_t)c * H_ + h] : 0.f;
        tile[ho][c] = f2bf(v);
    }
    __syncthreads();
    #pragma unroll
    for (int rep = 0; rep < 2; ++rep) {
        int task = rep * 256 + t;          // 0..511  = 64 rows * 8 chunks
        int hh = task >> 3;
        int j  = task & 7;
        int hw = h0 + hh;
        if (hw < H_) {
            *reinterpret_cast<uint4*>(&xT[((size_t)b * H_ + hw) * 64 + j * 8]) =
                *reinterpret_cast<const uint4*>(&tile[hh][j * 8]);
        }
    }
}

// ---------------------------------------------------------------------------
// Kernel 3: persistent 8-tile pipeline, 512 threads = 8 waves (4 og x 2 hh).
// Key fix vs all prior rounds: W fragments (wr[14], 56 VGPR) are PINNED in
// registers via an empty "+v" asm — prior rounds rematerialized W2 global
// loads inside the MFMA loop (VGPR_Count 60..96 < wr size), serializing
// ~14 L2 round-trips per tile.
// Center slot is NOT staged: its rows are h-contiguous, prefetched to regs
// one tile ahead. feat = 6 neighbor slots, double-buffered, 48 KB.
// Staging: 24 global_load_lds per tile (8 rows x 128B each, XOR-swizzled
// source), 3 per wave; counted vmcnt never waits on store-acks.
// ---------------------------------------------------------------------------
__global__ __launch_bounds__(512, 4) void conv_main(
        const unsigned short* __restrict__ xT,
        const unsigned short* __restrict__ W2,
        const int*   __restrict__ nb,
        const float* __restrict__ bias,
        const float* __restrict__ inv_tv,
        const unsigned short* __restrict__ zbuf,
        float* __restrict__ out) {
    __shared__ __align__(16) unsigned short feat[2][6][HT2][64]; // 49,152 B

    int bid = blockIdx.x;
    int swz   = (bid & 7) * CPX2 + (bid >> 3);   // bijective XCD swizzle
    int gbase = swz * TPBLK;

    int t = threadIdx.x;
    int w = t >> 6;          // wave 0..7
    int l = t & 63;

    // staging lane constants: wave w owns instrs m = w*3+c, c=0..2
    int lrow = l >> 3;                  // row within an 8-row quarter
    int jsrc = (l & 7) ^ lrow;          // source 16B unit (inverse of read swz)
    int qm[3], rq[3];
    #pragma unroll
    for (int c = 0; c < 3; ++c) {
        int m = w * 3 + c;              // 0..23
        qm[c] = m >> 2;                 // neighbor slot 0..5
        rq[c] = (m & 3) * 8;            // row quarter base
    }

    // compute lane constants
    int og = w & 3, hh = w >> 2;
    int lr = l & 15, lg = l >> 4;
    int hrow = hh * 16 + lr;            // 0..31
    int sw8  = hrow & 7;

    // W fragments -> registers, then PIN (non-rematerializable)
    const bf16x8* __restrict__ Wf = reinterpret_cast<const bf16x8*>(W2);
    bf16x8 wr[NSTEP];
    #pragma unroll
    for (int s = 0; s < NSTEP; ++s) wr[s] = Wf[(s * 4 + og) * 64 + l];
    #pragma unroll
    for (int s = 0; s < NSTEP; ++s) asm volatile("" : "+v"(wr[s]));

    float inv = *inv_tv;
    float bv[4];
    #pragma unroll
    for (int r = 0; r < 4; ++r) bv[r] = bias[og * 16 + lg * 4 + r];

    int nbv[3];          // neighbor rows for the tile staged next
    int bn, h0n;         // b / h0 of that tile
    bf16x8 cc[2][2];     // center fragments, double-buffered by tile parity

    // ---- prologue: nb_0 -> stage_0 + center_0 -> nb_1 --------------------
    {
        int b0  = gbase / TPB;
        int h00 = (gbase - b0 * TPB) * HT2;
        #pragma unroll
        for (int c = 0; c < 3; ++c) {
            int h = h00 + rq[c] + lrow;
            nbv[c] = (h < H_) ? nb[h * 6 + qm[c]] : -1;
        }
        const unsigned short* xb = xT + (size_t)b0 * H_ * 64;
        #pragma unroll
        for (int c = 0; c < 3; ++c) {
            int n = nbv[c];
            const unsigned short* src = (n >= 0)
                ? (xb + (size_t)n * 64 + jsrc * 8) : (zbuf + jsrc * 8);
            __builtin_amdgcn_global_load_lds((glb_u32*)src,
                (lds_u32*)&feat[0][qm[c]][rq[c]][0], 16, 0, 0);
        }
        int hcl = h00 + hrow; if (hcl >= H_) hcl = H_ - 1;
        const bf16x8* crow = reinterpret_cast<const bf16x8*>(xb + (size_t)hcl * 64);
        cc[0][0] = crow[lg];
        cc[0][1] = crow[4 + lg];
        int g1 = gbase + 1;
        bn  = g1 / TPB;
        h0n = (g1 - bn * TPB) * HT2;
        #pragma unroll
        for (int c = 0; c < 3; ++c) {
            int h = h0n + rq[c] + lrow;
            nbv[c] = (h < H_) ? nb[h * 6 + qm[c]] : -1;
        }
    }

    // ---- main loop over 8 tiles (fully unrolled) -------------------------
    #pragma unroll
    for (int i = 0; i < TPBLK; ++i) {
        // A: stage tile i+1 (implicit wait on nbv regs => stage_i retired
        //    before any wave reaches the barrier) + center_{i+1} prefetch
        if (i < TPBLK - 1) {
            const unsigned short* xb = xT + (size_t)bn * H_ * 64;
            int nbuf = (i + 1) & 1;
            #pragma unroll
            for (int c = 0; c < 3; ++c) {
                int n = nbv[c];
                const unsigned short* src = (n >= 0)
                    ? (xb + (size_t)n * 64 + jsrc * 8) : (zbuf + jsrc * 8);
                __builtin_amdgcn_global_load_lds((glb_u32*)src,
                    (lds_u32*)&feat[nbuf][qm[c]][rq[c]][0], 16, 0, 0);
            }
            int hcl = h0n + hrow; if (hcl >= H_) hcl = H_ - 1;
            const bf16x8* crow = reinterpret_cast<const bf16x8*>(xb + (size_t)hcl * 64);
            cc[nbuf][0] = crow[lg];
            cc[nbuf][1] = crow[4 + lg];
        }
        // B: prefetch nb rows for tile i+2
        if (i < TPBLK - 2) {
            int g2 = gbase + i + 2;
            bn  = g2 / TPB;
            h0n = (g2 - bn * TPB) * HT2;
            #pragma unroll
            for (int c = 0; c < 3; ++c) {
                int h = h0n + rq[c] + lrow;
                nbv[c] = (h < H_) ? nb[h * 6 + qm[c]] : -1;
            }
        }
        // C: counted wait. Per-wave FIFO newest-first at this point:
        //    i<6:  nb_{i+2}(3) + center_{i+1}(2) + stage_{i+1}(3) + stores_{i-1}(4) = 12
        //    i==6: center_7(2) + stage_7(3) + stores_5(4) = 9
        //    i==7: stores_6(4) + center_7(2) = 6  (forces stage_7 retirement)
        if (i == TPBLK - 1)
            asm volatile("s_waitcnt vmcnt(6)" ::: "memory");
        else if (i == TPBLK - 2)
            asm volatile("s_waitcnt vmcnt(9)" ::: "memory");
        else
            asm volatile("s_waitcnt vmcnt(12)" ::: "memory");
        __builtin_amdgcn_s_barrier();
        __builtin_amdgcn_sched_barrier(0);

        // E: compute tile i — 2 center (regs) + 12 LDS frags, 14 MFMA
        int cb = i & 1;
        f32x4 acc = (f32x4){0.f, 0.f, 0.f, 0.f};
        acc = __builtin_amdgcn_mfma_f32_16x16x32_bf16(wr[0], cc[cb][0], acc, 0, 0, 0);
        acc = __builtin_amdgcn_mfma_f32_16x16x32_bf16(wr[1], cc[cb][1], acc, 0, 0, 0);
        #pragma unroll
        for (int q = 0; q < 6; ++q) {
            bf16x8 fa = *reinterpret_cast<const bf16x8*>(
                    &feat[cb][q][hrow][(lg ^ sw8) * 8]);
            bf16x8 fb = *reinterpret_cast<const bf16x8*>(
                    &feat[cb][q][hrow][((4 + lg) ^ sw8) * 8]);
            acc = __builtin_amdgcn_mfma_f32_16x16x32_bf16(wr[2 + 2 * q], fa, acc, 0, 0, 0);
            acc = __builtin_amdgcn_mfma_f32_16x16x32_bf16(wr[3 + 2 * q], fb, acc, 0, 0, 0);
        }

        // F: epilogue for tile i (4 stores)
        int g    = gbase + i;
        int curb = g / TPB;
        int curh = (g - curb * TPB) * HT2 + hrow;
        if (curh < H_) {
            float* ob = out + (size_t)curb * COUT * H_ + curh;
            #pragma unroll
            for (int r = 0; r < 4; ++r)
                ob[(size_t)(og * 16 + lg * 4 + r) * H_] = acc[r] * inv + bv[r];
        }

        // G: all reads of buf[i&1] done before next iter's staging overwrites
        __builtin_amdgcn_s_barrier();
    }
}

// ---------------------------------------------------------------------------
extern "C" void kernel_launch(void* const* d_in, const int* in_sizes, int n_in,
                              void* d_out, int out_size, void* d_ws, size_t ws_size,
                              hipStream_t stream) {
    const float* x    = (const float*)d_in[0];
    const int*   nb   = (const int*)  d_in[1];
    const float* wc   = (const float*)d_in[2];
    const float* wn   = (const float*)d_in[3];
    const float* bias = (const float*)d_in[4];
    float* out = (float*)d_out;

    char* ws = (char*)d_ws;
    unsigned short* W2     = (unsigned short*)ws;            // 57,344 B
    float*          inv_tv = (float*)(ws + 57344);           // 4 B
    unsigned short* zbuf   = (unsigned short*)(ws + 57472);  // 128 B zero
    unsigned short* xT     = (unsigned short*)(ws + 57600);  // 60,784,640 B

    prep_weights<<<112, 256, 0, stream>>>(wc, wn, nb, W2, inv_tv, zbuf);

    dim3 tgrid(NHT, B_);
    transpose_bf16<<<tgrid, 256, 0, stream>>>(x, xT);
    conv_main<<<NBLK, 512, 0, stream>>>(xT, W2, nb, bias, inv_tv, zbuf, out);
}

// Round 8
// 128.059 us; speedup vs baseline: 1.6096x; 1.0124x over previous
//
#include <hip/hip_runtime.h>
#include <hip/hip_bf16.h>

// Problem constants
#define B_    256
#define CIN   64
#define COUT  64
#define H_    1855
#define K_    6
#define NSTEP 14           // 448 / 32 (K per MFMA)
#define HT    64           // h-tile for transpose kernel
#define NHT   29           // ceil(1855/64)

// conv_main tiling
#define HT2   32           // h rows per conv tile
#define TPB   58           // tiles per b = ceil(1855/32)
#define NTILE (TPB * B_)   // 14848
#define TPBLK 8            // tiles per block
#define NBLK  (NTILE / TPBLK)   // 1856, % 8 == 0
#define CPX2  (NBLK / 8)        // 232

typedef __bf16 bf16x8 __attribute__((ext_vector_type(8)));
typedef float  f32x4  __attribute__((ext_vector_type(4)));

typedef __attribute__((address_space(3))) unsigned int       lds_u32;
typedef const __attribute__((address_space(1))) unsigned int glb_u32;

static __device__ inline unsigned short f2bf(float f) {
    __hip_bfloat16 h = __float2bfloat16(f);
    return *reinterpret_cast<unsigned short*>(&h);
}

// ---------------------------------------------------------------------------
// Kernel 1: pack weights into MFMA A-fragment order (bf16) + 1/total_valid.
// Also zeroes the 128-B zbuf (branch-free source for invalid neighbors).
// ---------------------------------------------------------------------------
__global__ void prep_weights(const float* __restrict__ wc,
                             const float* __restrict__ wn,
                             const int*   __restrict__ nb,
                             unsigned short* __restrict__ W2,
                             float* __restrict__ inv_tv,
                             unsigned short* __restrict__ zbuf) {
    int e = blockIdx.x * 256 + threadIdx.x;     // 0 .. 28671
    int j = e & 7;
    int l = (e >> 3) & 63;
    int t = (e >> 9) & 3;
    int s = e >> 11;
    int o = t * 16 + (l & 15);
    int k = s * 32 + (l >> 4) * 8 + j;
    int slot = k >> 6;
    int c = k & 63;
    float v = (slot == 0) ? wc[o * 64 + c]
                          : wn[(o * 64 + c) * 6 + (slot - 1)];
    W2[e] = f2bf(v);
    if (blockIdx.x == 0 && threadIdx.x < 64) zbuf[threadIdx.x] = 0;
    if (e == 0) {
        int cnt = 1;
        #pragma unroll
        for (int q = 0; q < 6; ++q) cnt += (nb[q] >= 0) ? 1 : 0;
        *inv_tv = 1.0f / (float)cnt;
    }
}

// ---------------------------------------------------------------------------
// Kernel 2: transpose + convert  x (B, C, H) fp32  ->  xT (B, H, C) bf16
// ---------------------------------------------------------------------------
__global__ void transpose_bf16(const float* __restrict__ x,
                               unsigned short* __restrict__ xT) {
    __shared__ __align__(16) unsigned short tile[64][72];  // +8 pad
    int b  = blockIdx.y;
    int h0 = blockIdx.x * HT;
    int t  = threadIdx.x;
    int ho = t & 63;
    int cq = t >> 6;                       // 0..3
    const float* xb = x + (size_t)b * CIN * H_;
    int h = h0 + ho;
    #pragma unroll
    for (int i = 0; i < 16; ++i) {
        int c = i * 4 + cq;
        float v = (h < H_) ? xb[(size_t)c * H_ + h] : 0.f;
        tile[ho][c] = f2bf(v);
    }
    __syncthreads();
    #pragma unroll
    for (int rep = 0; rep < 2; ++rep) {
        int task = rep * 256 + t;          // 0..511  = 64 rows * 8 chunks
        int hh = task >> 3;
        int j  = task & 7;
        int hw = h0 + hh;
        if (hw < H_) {
            *reinterpret_cast<uint4*>(&xT[((size_t)b * H_ + hw) * 64 + j * 8]) =
                *reinterpret_cast<const uint4*>(&tile[hh][j * 8]);
        }
    }
}

// ---------------------------------------------------------------------------
// Kernel 3: persistent 8-tile pipeline, 512 threads = 8 waves (4 og x 2 hh).
// KEY FIX vs rounds 2-7: nb-prefetch (B') is issued BEFORE staging (A') each
// iteration, with ping-ponged nbv registers. Previously A consumed nbv whose
// implicit compiler s_waitcnt was vmcnt(4) (only stores newer) — which, since
// vmcnt is a counter, ALSO drained stage_{i+1}/center_{i+1} at the top of
// every iteration, reducing the pipeline to ~one-E-phase of slack and letting
// HBM stragglers (10% of gather lines miss L2) stall all 8 barrier-coupled
// waves. With B' first, the implicit wait at A' is vmcnt(12), leaving the
// current staging in flight until the explicit counted wait at C.
// ---------------------------------------------------------------------------
__global__ __launch_bounds__(512, 4) void conv_main(
        const unsigned short* __restrict__ xT,
        const unsigned short* __restrict__ W2,
        const int*   __restrict__ nb,
        const float* __restrict__ bias,
        const float* __restrict__ inv_tv,
        const unsigned short* __restrict__ zbuf,
        float* __restrict__ out) {
    __shared__ __align__(16) unsigned short feat[2][6][HT2][64]; // 49,152 B

    int bid = blockIdx.x;
    int swz   = (bid & 7) * CPX2 + (bid >> 3);   // bijective XCD swizzle
    int gbase = swz * TPBLK;

    int t = threadIdx.x;
    int w = t >> 6;          // wave 0..7
    int l = t & 63;

    // staging lane constants: wave w owns instrs m = w*3+c, c=0..2
    int lrow = l >> 3;                  // row within an 8-row quarter
    int jsrc = (l & 7) ^ lrow;          // source 16B unit (inverse of read swz)
    int qm[3], rq[3];
    #pragma unroll
    for (int c = 0; c < 3; ++c) {
        int m = w * 3 + c;              // 0..23
        qm[c] = m >> 2;                 // neighbor slot 0..5
        rq[c] = (m & 3) * 8;            // row quarter base
    }

    // compute lane constants
    int og = w & 3, hh = w >> 2;
    int lr = l & 15, lg = l >> 4;
    int hrow = hh * 16 + lr;            // 0..31
    int sw8  = hrow & 7;

    // W fragments -> registers (allocator may park in AGPRs; fine)
    const bf16x8* __restrict__ Wf = reinterpret_cast<const bf16x8*>(W2);
    bf16x8 wr[NSTEP];
    #pragma unroll
    for (int s = 0; s < NSTEP; ++s) wr[s] = Wf[(s * 4 + og) * 64 + l];
    #pragma unroll
    for (int s = 0; s < NSTEP; ++s) asm volatile("" : "+v"(wr[s]));

    float inv = *inv_tv;
    float bv[4];
    #pragma unroll
    for (int r = 0; r < 4; ++r) bv[r] = bias[og * 16 + lg * 4 + r];

    // nbv[p] holds neighbor rows for tile t with t&1 == p (ping-pong;
    // loop is fully unrolled so indexing is compile-time static).
    int nbv[2][3];
    bf16x8 cc[2][2];     // center fragments, by tile parity

    // ---- prologue: nb_0 -> stage_0 + center_0 -> nb_1 --------------------
    {
        int b0  = gbase / TPB;
        int h00 = (gbase - b0 * TPB) * HT2;
        int nb0[3];
        #pragma unroll
        for (int c = 0; c < 3; ++c) {
            int h = h00 + rq[c] + lrow;
            nb0[c] = (h < H_) ? nb[h * 6 + qm[c]] : -1;
        }
        const unsigned short* xb = xT + (size_t)b0 * H_ * 64;
        int hcl = h00 + hrow; if (hcl >= H_) hcl = H_ - 1;
        const bf16x8* crow = reinterpret_cast<const bf16x8*>(xb + (size_t)hcl * 64);
        cc[0][0] = crow[lg];
        cc[0][1] = crow[4 + lg];
        #pragma unroll
        for (int c = 0; c < 3; ++c) {
            int n = nb0[c];
            const unsigned short* src = (n >= 0)
                ? (xb + (size_t)n * 64 + jsrc * 8) : (zbuf + jsrc * 8);
            __builtin_amdgcn_global_load_lds((glb_u32*)src,
                (lds_u32*)&feat[0][qm[c]][rq[c]][0], 16, 0, 0);
        }
        // nb for tile 1 -> slot 1
        int g1 = gbase + 1;
        int b1 = g1 / TPB;
        int h01 = (g1 - b1 * TPB) * HT2;
        #pragma unroll
        for (int c = 0; c < 3; ++c) {
            int h = h01 + rq[c] + lrow;
            nbv[1][c] = (h < H_) ? nb[h * 6 + qm[c]] : -1;
        }
    }

    // ---- main loop over 8 tiles (fully unrolled) -------------------------
    #pragma unroll
    for (int i = 0; i < TPBLK; ++i) {
        // B': prefetch nb rows for tile i+2 into slot (i+2)&1 == i&1.
        //     Pure ALU + fresh loads — no implicit vmcnt here.
        if (i < TPBLK - 2) {
            int g2 = gbase + i + 2;
            int b2 = g2 / TPB;
            int h02 = (g2 - b2 * TPB) * HT2;
            #pragma unroll
            for (int c = 0; c < 3; ++c) {
                int h = h02 + rq[c] + lrow;
                nbv[i & 1][c] = (h < H_) ? nb[h * 6 + qm[c]] : -1;
            }
        }
        // A': stage tile i+1 (consumes nbv[(i+1)&1] -> implicit vmcnt(12),
        //     leaves stage_i in flight) + center_{i+1} prefetch to regs.
        if (i < TPBLK - 1) {
            int g1 = gbase + i + 1;
            int b1 = g1 / TPB;
            int h01 = (g1 - b1 * TPB) * HT2;
            const unsigned short* xb = xT + (size_t)b1 * H_ * 64;
            int nbuf = (i + 1) & 1;
            int hcl = h01 + hrow; if (hcl >= H_) hcl = H_ - 1;
            const bf16x8* crow = reinterpret_cast<const bf16x8*>(xb + (size_t)hcl * 64);
            cc[nbuf][0] = crow[lg];
            cc[nbuf][1] = crow[4 + lg];
            #pragma unroll
            for (int c = 0; c < 3; ++c) {
                int n = nbv[nbuf][c];
                const unsigned short* src = (n >= 0)
                    ? (xb + (size_t)n * 64 + jsrc * 8) : (zbuf + jsrc * 8);
                __builtin_amdgcn_global_load_lds((glb_u32*)src,
                    (lds_u32*)&feat[nbuf][qm[c]][rq[c]][0], 16, 0, 0);
            }
        }
        // C: counted wait for stage_i. Newest-first per-wave FIFO here:
        //    i<=5: A'(i) center+stage(5) + B'(i) nb(3) + F(i-1) stores(4) = 12
        //    i==6: A'(6)(5) + stores(4) = 9
        //    i==7: stores(4) = 4
        if (i == TPBLK - 1)
            asm volatile("s_waitcnt vmcnt(4)" ::: "memory");
        else if (i == TPBLK - 2)
            asm volatile("s_waitcnt vmcnt(9)" ::: "memory");
        else
            asm volatile("s_waitcnt vmcnt(12)" ::: "memory");
        __builtin_amdgcn_s_barrier();
        __builtin_amdgcn_sched_barrier(0);

        // E: compute tile i — 2 center (regs) + 12 LDS frags, 14 MFMA
        int cb = i & 1;
        f32x4 acc = (f32x4){0.f, 0.f, 0.f, 0.f};
        acc = __builtin_amdgcn_mfma_f32_16x16x32_bf16(wr[0], cc[cb][0], acc, 0, 0, 0);
        acc = __builtin_amdgcn_mfma_f32_16x16x32_bf16(wr[1], cc[cb][1], acc, 0, 0, 0);
        #pragma unroll
        for (int q = 0; q < 6; ++q) {
            bf16x8 fa = *reinterpret_cast<const bf16x8*>(
                    &feat[cb][q][hrow][(lg ^ sw8) * 8]);
            bf16x8 fb = *reinterpret_cast<const bf16x8*>(
                    &feat[cb][q][hrow][((4 + lg) ^ sw8) * 8]);
            acc = __builtin_amdgcn_mfma_f32_16x16x32_bf16(wr[2 + 2 * q], fa, acc, 0, 0, 0);
            acc = __builtin_amdgcn_mfma_f32_16x16x32_bf16(wr[3 + 2 * q], fb, acc, 0, 0, 0);
        }

        // F: epilogue for tile i (4 stores)
        int g    = gbase + i;
        int curb = g / TPB;
        int curh = (g - curb * TPB) * HT2 + hrow;
        if (curh < H_) {
            float* ob = out + (size_t)curb * COUT * H_ + curh;
            #pragma unroll
            for (int r = 0; r < 4; ++r)
                ob[(size_t)(og * 16 + lg * 4 + r) * H_] = acc[r] * inv + bv[r];
        }

        // G: all reads of buf[i&1] done before next iter's staging overwrites
        __builtin_amdgcn_s_barrier();
    }
}

// ---------------------------------------------------------------------------
extern "C" void kernel_launch(void* const* d_in, const int* in_sizes, int n_in,
                              void* d_out, int out_size, void* d_ws, size_t ws_size,
                              hipStream_t stream) {
    const float* x    = (const float*)d_in[0];
    const int*   nb   = (const int*)  d_in[1];
    const float* wc   = (const float*)d_in[2];
    const float* wn   = (const float*)d_in[3];
    const float* bias = (const float*)d_in[4];
    float* out = (float*)d_out;

    char* ws = (char*)d_ws;
    unsigned short* W2     = (unsigned short*)ws;            // 57,344 B
    float*          inv_tv = (float*)(ws + 57344);           // 4 B
    unsigned short* zbuf   = (unsigned short*)(ws + 57472);  // 128 B zero
    unsigned short* xT     = (unsigned short*)(ws + 57600);  // 60,784,640 B

    prep_weights<<<112, 256, 0, stream>>>(wc, wn, nb, W2, inv_tv, zbuf);

    dim3 tgrid(NHT, B_);
    transpose_bf16<<<tgrid, 256, 0, stream>>>(x, xT);
    conv_main<<<NBLK, 512, 0, stream>>>(xT, W2, nb, bias, inv_tv, zbuf, out);
}